// Round 1
// baseline (824.848 us; speedup 1.0000x reference)
//
#include <hip/hip_runtime.h>

typedef _Float16 f16;
typedef _Float16 half8 __attribute__((ext_vector_type(8)));
typedef float f32x4 __attribute__((ext_vector_type(4)));

#define TOK 49
#define HEADS 8

// XOR swizzle: spreads rows across LDS banks (row stride 1024B / 128B would be
// a 16-way conflict on ds_read_b128 otherwise; swizzled -> 2-way = free)
__device__ __forceinline__ int swzX(int row, int kb) { return row * 1024 + (kb ^ ((row & 7) << 4)); }
__device__ __forceinline__ int swz64(int row, int cb) { return row * 128 + (cb ^ ((row & 7) << 4)); }

// ws layout: Wt[3][512 n][512 k] f16, Wt[m][n][k] = w_m[k*512+n]
__global__ void prep_weights(const float* __restrict__ wq,
                             const float* __restrict__ wk,
                             const float* __restrict__ wv,
                             f16* __restrict__ wt) {
    int gid = blockIdx.x * 256 + threadIdx.x;   // 0 .. 3*512*512-1
    int m   = gid >> 18;
    int rem = gid & 262143;
    int n   = rem >> 9;
    int k   = rem & 511;
    const float* w = (m == 0) ? wq : (m == 1) ? wk : wv;
    wt[gid] = (f16)w[k * 512 + n];
}

__global__ __launch_bounds__(256, 1)
void swin_attn(const float* __restrict__ x,
               const float* __restrict__ bqv,
               const float* __restrict__ bkv,
               const float* __restrict__ bvv,
               const float* __restrict__ pos_bias,
               const f16* __restrict__ wt,
               float* __restrict__ out) {
    __shared__ f16   Xs [64 * 512];   // 64KB, swizzled, rows 49..63 zero
    __shared__ f16   Qs [64 * 64];    // 8KB each
    __shared__ f16   Ks [64 * 64];
    __shared__ f16   Vts[64 * 64];    // V transposed: Vts[d][t2]
    __shared__ f16   Ps [64 * 64];
    __shared__ float pbs[TOK * TOK];  // 9.6KB

    const int w    = blockIdx.x;      // window id = b*64 + wy*8 + wx
    const int bb   = w >> 6;
    const int wy   = (w >> 3) & 7;
    const int wx   = w & 7;
    const int tid  = threadIdx.x;
    const int wave = tid >> 6;
    const int lane = tid & 63;
    const int l15  = lane & 15;
    const int lg   = lane >> 4;

    // ---- stage X window -> LDS f16 (swizzled), zero pad rows ----
    #pragma unroll
    for (int it = 0; it < 16; ++it) {
        int idx = (it * 256 + tid) * 8;
        int m = idx >> 9;
        int k = idx & 511;
        uint4 pack;
        if (m < TOK) {
            int i = m / 7, j = m - i * 7;
            const float* src = x + (((size_t)(bb * 56 + wy * 7 + i)) * 56 + (wx * 7 + j)) * 512 + k;
            float4 f0 = ((const float4*)src)[0];
            float4 f1 = ((const float4*)src)[1];
            alignas(16) f16 hh[8] = {(f16)f0.x, (f16)f0.y, (f16)f0.z, (f16)f0.w,
                                     (f16)f1.x, (f16)f1.y, (f16)f1.z, (f16)f1.w};
            pack = *(const uint4*)hh;
        } else {
            pack = make_uint4(0u, 0u, 0u, 0u);
        }
        *(uint4*)((char*)Xs + swzX(m, k * 2)) = pack;
    }
    __syncthreads();

    const float scale = 0.044194173824159216f;  // 1/sqrt(512)

    for (int h = 0; h < HEADS; ++h) {
        // stage this head's positional bias (read after next barrier)
        for (int idx = tid; idx < TOK * TOK; idx += 256)
            pbs[idx] = pos_bias[h * TOK * TOK + idx];

        // ---- QKV projection for this head's 64 channels ----
        // wave handles n-columns [wave*16, wave*16+16) of Q, K and V
        f32x4 accQ[4], accK[4], accV[4];
        #pragma unroll
        for (int mt = 0; mt < 4; ++mt) {
            accQ[mt] = {0.f, 0.f, 0.f, 0.f};
            accK[mt] = {0.f, 0.f, 0.f, 0.f};
            accV[mt] = {0.f, 0.f, 0.f, 0.f};
        }
        const int ncol = h * 64 + wave * 16 + l15;       // global out channel
        const f16* pQ = wt + (size_t)(ncol) * 512;
        const f16* pK = wt + (size_t)(512 + ncol) * 512;
        const f16* pV = wt + (size_t)(1024 + ncol) * 512;
        #pragma unroll
        for (int ks = 0; ks < 16; ++ks) {
            const int kk = ks * 32 + lg * 8;
            half8 a[4];
            #pragma unroll
            for (int mt = 0; mt < 4; ++mt)
                a[mt] = *(const half8*)((char*)Xs + swzX(mt * 16 + l15, kk * 2));
            half8 fQ = *(const half8*)(pQ + kk);
            half8 fK = *(const half8*)(pK + kk);
            half8 fV = *(const half8*)(pV + kk);
            #pragma unroll
            for (int mt = 0; mt < 4; ++mt) {
                accQ[mt] = __builtin_amdgcn_mfma_f32_16x16x32_f16(a[mt], fQ, accQ[mt], 0, 0, 0);
                accK[mt] = __builtin_amdgcn_mfma_f32_16x16x32_f16(a[mt], fK, accK[mt], 0, 0, 0);
                accV[mt] = __builtin_amdgcn_mfma_f32_16x16x32_f16(a[mt], fV, accV[mt], 0, 0, 0);
            }
        }

        // epilogue: +bias, ->f16, Q/K row-major, V transposed (for PV B-frags)
        const float biasQ = bqv[ncol];
        const float biasK = bkv[ncol];
        const float biasV = bvv[ncol];
        const int nloc = wave * 16 + l15;
        #pragma unroll
        for (int mt = 0; mt < 4; ++mt) {
            const int m0 = mt * 16 + lg * 4;
            #pragma unroll
            for (int r = 0; r < 4; ++r) {
                *(f16*)((char*)Qs + swz64(m0 + r, nloc * 2)) = (f16)(accQ[mt][r] + biasQ);
                *(f16*)((char*)Ks + swz64(m0 + r, nloc * 2)) = (f16)(accK[mt][r] + biasK);
            }
            alignas(8) f16 vv[4];
            #pragma unroll
            for (int r = 0; r < 4; ++r) vv[r] = (f16)(accV[mt][r] + biasV);
            *(uint2*)((char*)Vts + swz64(nloc, m0 * 2)) = *(const uint2*)vv;
        }
        __syncthreads();

        // ---- S = Q K^T  (wave -> M-tile == wave) ----
        f32x4 sacc[4];
        #pragma unroll
        for (int nt = 0; nt < 4; ++nt) sacc[nt] = {0.f, 0.f, 0.f, 0.f};
        half8 qa[2];
        #pragma unroll
        for (int ks = 0; ks < 2; ++ks)
            qa[ks] = *(const half8*)((char*)Qs + swz64(wave * 16 + l15, (ks * 32 + lg * 8) * 2));
        #pragma unroll
        for (int nt = 0; nt < 4; ++nt) {
            #pragma unroll
            for (int ks = 0; ks < 2; ++ks) {
                half8 kb = *(const half8*)((char*)Ks + swz64(nt * 16 + l15, (ks * 32 + lg * 8) * 2));
                sacc[nt] = __builtin_amdgcn_mfma_f32_16x16x32_f16(qa[ks], kb, sacc[nt], 0, 0, 0);
            }
        }

        // ---- softmax (rows spread over 16-lane groups; shfl_xor reduce) ----
        #pragma unroll
        for (int r = 0; r < 4; ++r) {
            const int q  = wave * 16 + lg * 4 + r;
            const int qp = (q < TOK) ? q : 0;
            float sv[4];
            float rmax = -3.4028235e38f;
            #pragma unroll
            for (int nt = 0; nt < 4; ++nt) {
                const int t2 = nt * 16 + l15;
                const int tp = (t2 < TOK) ? t2 : 0;
                float s = sacc[nt][r] * scale + pbs[qp * TOK + tp];
                const bool valid = (q < TOK) && (t2 < TOK) && (t2 != q);
                s = valid ? s : -3.4028235e38f;   // eye-mask = finfo.min semantics
                sv[nt] = s;
                rmax = fmaxf(rmax, s);
            }
            #pragma unroll
            for (int md = 1; md < 16; md <<= 1)
                rmax = fmaxf(rmax, __shfl_xor(rmax, md));
            float rsum = 0.f;
            #pragma unroll
            for (int nt = 0; nt < 4; ++nt) {
                float e = __expf(sv[nt] - rmax);
                sv[nt] = e;
                rsum += e;
            }
            #pragma unroll
            for (int md = 1; md < 16; md <<= 1)
                rsum += __shfl_xor(rsum, md);
            const float inv = 1.f / rsum;
            #pragma unroll
            for (int nt = 0; nt < 4; ++nt)
                *(f16*)((char*)Ps + swz64(q, (nt * 16 + l15) * 2)) = (f16)(sv[nt] * inv);
        }
        __syncthreads();

        // ---- O = P V ----
        f32x4 oacc[4];
        #pragma unroll
        for (int nt = 0; nt < 4; ++nt) oacc[nt] = {0.f, 0.f, 0.f, 0.f};
        half8 pa[2];
        #pragma unroll
        for (int ks = 0; ks < 2; ++ks)
            pa[ks] = *(const half8*)((char*)Ps + swz64(wave * 16 + l15, (ks * 32 + lg * 8) * 2));
        #pragma unroll
        for (int nt = 0; nt < 4; ++nt) {
            #pragma unroll
            for (int ks = 0; ks < 2; ++ks) {
                half8 vb = *(const half8*)((char*)Vts + swz64(nt * 16 + l15, (ks * 32 + lg * 8) * 2));
                oacc[nt] = __builtin_amdgcn_mfma_f32_16x16x32_f16(pa[ks], vb, oacc[nt], 0, 0, 0);
            }
        }
        #pragma unroll
        for (int r = 0; r < 4; ++r) {
            const int q = wave * 16 + lg * 4 + r;
            if (q < TOK) {
                #pragma unroll
                for (int nt = 0; nt < 4; ++nt)
                    out[((size_t)w * TOK + q) * 512 + h * 64 + nt * 16 + l15] = oacc[nt][r];
            }
        }
        __syncthreads();   // protect Qs/Ks/Vts/Ps/pbs reuse next head
    }
}

extern "C" void kernel_launch(void* const* d_in, const int* in_sizes, int n_in,
                              void* d_out, int out_size, void* d_ws, size_t ws_size,
                              hipStream_t stream) {
    const float* x  = (const float*)d_in[0];
    const float* wq = (const float*)d_in[1];
    const float* bq = (const float*)d_in[2];
    const float* wk = (const float*)d_in[3];
    const float* bk = (const float*)d_in[4];
    const float* wv = (const float*)d_in[5];
    const float* bv = (const float*)d_in[6];
    const float* pb = (const float*)d_in[7];
    f16*  wt  = (f16*)d_ws;            // 3*512*512*2 = 1.5MB scratch
    float* out = (float*)d_out;

    prep_weights<<<3072, 256, 0, stream>>>(wq, wk, wv, wt);
    swin_attn<<<2048, 256, 0, stream>>>(x, bq, bk, bv, pb, wt, out);
}